// Round 3
// baseline (4796.898 us; speedup 1.0000x reference)
//
#include <hip/hip_runtime.h>
#include <hip/hip_bf16.h>

typedef unsigned short u16;
typedef unsigned int u32;
typedef unsigned long long u64;
typedef short  s16x8 __attribute__((ext_vector_type(8)));
typedef float  f32x4 __attribute__((ext_vector_type(4)));

#define T_STEPS 512
#define BATCH   32
#define HID     512
#define EMBD    300
#define KPAD    320
#define NGATE   2048

// ---- workspace layout (bytes) ----
#define XZ_OFF   0ull
#define XZ_BYTES (512ull*32*2048*4)          // 134,217,728  f32 [t][b][4H]
#define UB_OFF   (XZ_OFF + XZ_BYTES)
#define UB_BYTES (2048ull*512*2)             // 2,097,152  bf16 per-WG LDS images
#define WT_OFF   (UB_OFF + UB_BYTES)
#define WT_BYTES (2048ull*320*2)             // 1,310,720  bf16 [n][kpad] swizzled
#define HB_OFF   (WT_OFF + WT_BYTES)
#define HB_BYTES (2ull*32*512*2)             // 65,536  double-buffered h bf16 [b][512] (u32-packed)
#define FL_OFF   (HB_OFF + HB_BYTES)
#define FL_BYTES 128ull                      // 32 flags

__device__ inline u16 f2b(float f) {
  u32 u = __builtin_bit_cast(u32, f);
  return (u16)((u + 0x7fffu + ((u >> 16) & 1u)) >> 16);
}

// L2-bypassing (MALL-coherent) accessors: relaxed agent-scope atomics lower to
// global_load/store ... sc0 sc1 on gfx950 — no wbl2/inv fences needed anywhere.
__device__ inline u64 ld64_agent(const u64* p) {
  return __hip_atomic_load(p, __ATOMIC_RELAXED, __HIP_MEMORY_SCOPE_AGENT);
}
__device__ inline u32 ld32_agent(const u32* p) {
  return __hip_atomic_load(p, __ATOMIC_RELAXED, __HIP_MEMORY_SCOPE_AGENT);
}
__device__ inline void st32_agent(u32* p, u32 v) {
  __hip_atomic_store(p, v, __ATOMIC_RELAXED, __HIP_MEMORY_SCOPE_AGENT);
}

// ---------- pack W: [300][2048] f32 -> wt[n][k] bf16, k padded to 320, swizzled ----------
__global__ __launch_bounds__(64) void pack_w(const float* __restrict__ W, u16* __restrict__ wt) {
  int n = blockIdx.x;               // 0..2047
  for (int i = 0; i < 5; ++i) {
    int k = i * 64 + threadIdx.x;   // 0..319
    float v = (k < EMBD) ? W[(size_t)k * NGATE + n] : 0.f;
    u32 off = ((u32)(2 * k)) ^ (((u32)(n & 7)) << 4);
    *(u16*)((char*)wt + (size_t)n * 640 + off) = f2b(v);
  }
}

// ---------- pack U: [512][2048] f32 -> per-WG col-major swizzled bf16 LDS image ----------
// WG w owns local cols nl=0..63 : gate g = nl&3, h-col j = w*16 + (nl>>2); global col = g*512 + j
__global__ __launch_bounds__(64) void pack_u(const float* __restrict__ U, u16* __restrict__ ub) {
  int blk = blockIdx.x;             // 0..2047  = w*64 + nl
  int w = blk >> 6, nl = blk & 63;
  int gcol = (nl & 3) * 512 + w * 16 + (nl >> 2);
  for (int i = 0; i < 8; ++i) {
    int k = i * 64 + threadIdx.x;   // 0..511
    float v = U[(size_t)k * NGATE + gcol];
    u32 off = ((u32)(2 * k)) ^ (((u32)(nl & 7)) << 4);
    *(u16*)((char*)ub + (size_t)blk * 1024 + off) = f2b(v);
  }
}

// ---------- phase 1: xz[t][b][n] = emb[tok] @ W + bias (bf16 MFMA, f32 out) ----------
__global__ __launch_bounds__(256) void xz_gemm(const int* __restrict__ tokens,
                                               const float* __restrict__ emb,
                                               const u16* __restrict__ wt,
                                               const float* __restrict__ bias,
                                               float* __restrict__ xz) {
  extern __shared__ char smem[];
  const int tid = threadIdx.x;
  const int lane = tid & 63, wv = tid >> 6;
  const int m0 = (blockIdx.x >> 5) * 64;
  const int n0 = (blockIdx.x & 31) * 64;

  { // stage A: 64 rows of emb gather, f32 -> bf16, chunk layout
    int row = tid >> 2, q = tid & 3;
    int tok = tokens[m0 + row];
    const float* er = emb + (size_t)tok * EMBD;
    for (int i = 0; i < 10; ++i) {
      int k = q * 80 + i * 8;
      float4 lo = {0, 0, 0, 0}, hi = {0, 0, 0, 0};
      if (k <= 296) lo = *(const float4*)(er + k);
      if (k <= 292) hi = *(const float4*)(er + k + 4);
      u16 u[8] = {f2b(lo.x), f2b(lo.y), f2b(lo.z), f2b(lo.w),
                  f2b(hi.x), f2b(hi.y), f2b(hi.z), f2b(hi.w)};
      int kc = q * 10 + i;
      *(uint4*)(smem + kc * 1040 + row * 16) = *(uint4*)u;
    }
  }
  { // stage B: linear 40KB copy of pre-swizzled wt panel
    const uint4* src = (const uint4*)((const char*)wt + (size_t)n0 * 640);
    for (int i = 0; i < 10; ++i)
      *(uint4*)(smem + 41600 + (i * 256 + tid) * 16) = src[i * 256 + tid];
  }
  __syncthreads();

  const int mq = wv >> 1, nq = wv & 1;
  const int arow = lane & 15, kq4 = lane >> 4;
  f32x4 acc[2][2] = {};
#pragma unroll
  for (int ks = 0; ks < 10; ++ks) {
    s16x8 af[2], bfr[2];
#pragma unroll
    for (int mt = 0; mt < 2; ++mt) {
      int row = mq * 32 + mt * 16 + arow;
      int kc = ks * 4 + kq4;
      af[mt] = *(const s16x8*)(smem + kc * 1040 + row * 16);
    }
#pragma unroll
    for (int nt = 0; nt < 2; ++nt) {
      int nl = nq * 32 + nt * 16 + arow;
      u32 kb = (u32)(ks * 64 + (kq4 << 4));
      bfr[nt] = *(const s16x8*)(smem + 41600 + nl * 640 + (kb ^ (((u32)(nl & 7)) << 4)));
    }
#pragma unroll
    for (int mt = 0; mt < 2; ++mt)
#pragma unroll
      for (int nt = 0; nt < 2; ++nt)
        acc[mt][nt] = __builtin_amdgcn_mfma_f32_16x16x32_bf16(af[mt], bfr[nt], acc[mt][nt], 0, 0, 0);
  }
#pragma unroll
  for (int mt = 0; mt < 2; ++mt)
#pragma unroll
    for (int nt = 0; nt < 2; ++nt) {
      int gn = n0 + nq * 32 + nt * 16 + arow;
      float bv = bias[gn];
#pragma unroll
      for (int r = 0; r < 4; ++r) {
        int gm = m0 + mq * 32 + mt * 16 + (kq4 << 2) + r;
        int tt = gm & 511, bb = gm >> 9;         // tokens flat = b*T + t
        xz[((size_t)(tt * 32 + bb)) * NGATE + gn] = acc[mt][nt][r] + bv;
      }
    }
}

// ---------- phase 2: persistent 32-WG recurrent kernel ----------
// WG owns 64 U-cols in LDS (64KB). h double-buffered, u32-packed bf16, ALL cross-WG
// traffic via sc0/sc1-bypassing relaxed agent atomics -> no L2 writeback/invalidate.
__global__ __launch_bounds__(256) void lstm_persist(const float* __restrict__ xz,
                                                    const u16* __restrict__ ub,
                                                    u32* __restrict__ hbuf,
                                                    float* __restrict__ out,
                                                    u32* __restrict__ flags) {
  extern __shared__ char smem[];
  float* zlds = (float*)(smem + 65536);      // [32][68] f32
  const int tid = threadIdx.x;
  const int lane = tid & 63, wv = tid >> 6;
  const int wg = blockIdx.x;

  { // stage pre-swizzled U slice: linear 64KB copy (u16 elements: wg * 32768 = wg * 64KB)
    const uint4* src = (const uint4*)(ub + (size_t)wg * 32768);
    uint4* dst = (uint4*)smem;
    for (int i = 0; i < 16; ++i) dst[i * 256 + tid] = src[i * 256 + tid];
  }
  __syncthreads();

  const int b_g = tid & 31;                  // gate-stage batch
  const int pp  = tid >> 5;                  // 0..7 -> h-cols 2pp, 2pp+1
  const int arow = lane & 15, kq = lane >> 4;
  const int nl = wv * 16 + (lane & 15);
  const u32 bswz = ((u32)(nl & 7)) << 4;
  const int j0 = wg * 16;
  float c0 = 0.f, c1 = 0.f;

  float xzv[2][4];
  { // prefetch xz for t=0
    const float* p = xz + (size_t)b_g * NGATE + j0;
#pragma unroll
    for (int e = 0; e < 2; ++e) {
      int jl = 2 * pp + e;
#pragma unroll
      for (int g = 0; g < 4; ++g) xzv[e][g] = p[g * 512 + jl];
    }
  }

  for (int t = 0; t < T_STEPS; ++t) {
    if (t > 0) {  // z_lds = h @ U_slice ; h loaded via MALL-coherent u64 atomics
      const u64* hp = (const u64*)(hbuf + (t & 1) * 8192);
      const u64* r0 = hp + (size_t)arow * 128;        // row stride 1024B = 128 u64
      const u64* r1 = hp + (size_t)(arow + 16) * 128;
      f32x4 acc0 = {0, 0, 0, 0}, acc1 = {0, 0, 0, 0};
#pragma unroll
      for (int ks = 0; ks < 16; ++ks) {
        int qo = ks * 8 + kq * 2;                      // u64 offset: ks*64B + kq*16B
        union { u64 q[2]; s16x8 v; } a0, a1;
        a0.q[0] = ld64_agent(r0 + qo);
        a0.q[1] = ld64_agent(r0 + qo + 1);
        a1.q[0] = ld64_agent(r1 + qo);
        a1.q[1] = ld64_agent(r1 + qo + 1);
        s16x8 bb = *(const s16x8*)(smem + nl * 1024 + (((u32)(ks * 64 + (kq << 4))) ^ bswz));
        acc0 = __builtin_amdgcn_mfma_f32_16x16x32_bf16(a0.v, bb, acc0, 0, 0, 0);
        acc1 = __builtin_amdgcn_mfma_f32_16x16x32_bf16(a1.v, bb, acc1, 0, 0, 0);
      }
      int rb = kq * 4;
#pragma unroll
      for (int r = 0; r < 4; ++r) {
        zlds[(rb + r) * 68 + nl] = acc0[r];
        zlds[(rb + r + 16) * 68 + nl] = acc1[r];
      }
    }
    __syncthreads();

    // gates: thread handles (b_g, 2pp) and (b_g, 2pp+1)
    float hov[2], cov[2];
    float4 z0 = {0, 0, 0, 0}, z1 = {0, 0, 0, 0};
    if (t > 0) {
      z0 = *(const float4*)&zlds[b_g * 68 + 8 * pp];
      z1 = *(const float4*)&zlds[b_g * 68 + 8 * pp + 4];
    }
#pragma unroll
    for (int e = 0; e < 2; ++e) {
      float4 zr = e ? z1 : z0;
      float zi = zr.x + xzv[e][0];
      float zf = zr.y + xzv[e][1];
      float zg = zr.z + xzv[e][2];
      float zo = zr.w + xzv[e][3];
      float ig = 1.f / (1.f + __expf(-zi));
      float fg = 1.f / (1.f + __expf(-zf));
      float gg = 1.f - 2.f / (__expf(2.f * zg) + 1.f);
      float og = 1.f / (1.f + __expf(-zo));
      float cc = e ? c1 : c0;
      cc = fg * cc + ig * gg;
      float hh = og * (1.f - 2.f / (__expf(2.f * cc) + 1.f));
      if (e) c1 = cc; else c0 = cc;
      hov[e] = hh; cov[e] = cc;
    }
    if (t < T_STEPS - 1) {
      u32* hn = hbuf + ((t + 1) & 1) * 8192;
      u32 val = (u32)f2b(hov[0]) | ((u32)f2b(hov[1]) << 16);
      st32_agent(&hn[b_g * 256 + (j0 >> 1) + pp], val);   // one dword / thread, MALL-bound
    } else {
#pragma unroll
      for (int e = 0; e < 2; ++e) {
        int jl = 2 * pp + e;
        out[b_g * 512 + j0 + jl] = hov[e];
        out[16384 + b_g * 512 + j0 + jl] = cov[e];
      }
    }
    __syncthreads();   // hipcc drains vmcnt(0) before s_barrier: all h stores acked at MALL

    if (t < T_STEPS - 1) {
      if (tid == 0)    // publish: plain relaxed agent store (sc0 sc1), no wbl2
        st32_agent(&flags[wg], (u32)(t + 1));
      { // prefetch next xz while waiting
        const float* p = xz + ((size_t)(t + 1) * 32 + b_g) * NGATE + j0;
#pragma unroll
        for (int e = 0; e < 2; ++e) {
          int jl = 2 * pp + e;
#pragma unroll
          for (int g = 0; g < 4; ++g) xzv[e][g] = p[g * 512 + jl];
        }
      }
      if (wv == 0) {  // 32 lanes poll 32 flags (relaxed agent loads read MALL directly)
        u32 tgt = (u32)(t + 1);
        for (;;) {
          u32 v = (lane < 32) ? ld32_agent(&flags[lane]) : tgt;
          if (__all(v >= tgt)) break;
          __builtin_amdgcn_s_sleep(1);
        }
      }
      __syncthreads();  // orders every wave's h loads after flag observation; no L2 inv needed
    }
  }
}

extern "C" void kernel_launch(void* const* d_in, const int* in_sizes, int n_in,
                              void* d_out, int out_size, void* d_ws, size_t ws_size,
                              hipStream_t stream) {
  const int*   tokens = (const int*)d_in[0];
  const float* emb    = (const float*)d_in[1];
  const float* W      = (const float*)d_in[2];
  const float* U      = (const float*)d_in[3];
  const float* bias   = (const float*)d_in[4];
  float* out = (float*)d_out;
  char*  ws  = (char*)d_ws;

  float* xz   = (float*)(ws + XZ_OFF);
  u16*   ub   = (u16*)(ws + UB_OFF);
  u16*   wt   = (u16*)(ws + WT_OFF);
  u32*   hbuf = (u32*)(ws + HB_OFF);
  u32*   flags = (u32*)(ws + FL_OFF);

  hipMemsetAsync(flags, 0, FL_BYTES, stream);
  pack_w<<<2048, 64, 0, stream>>>(W, wt);
  pack_u<<<2048, 64, 0, stream>>>(U, ub);
  xz_gemm<<<8192, 256, 82560, stream>>>(tokens, emb, wt, bias, xz);
  lstm_persist<<<32, 256, 65536 + 32 * 68 * 4, stream>>>(xz, ub, hbuf, out, flags);
}

// Round 6
// 2060.544 us; speedup vs baseline: 2.3280x; 2.3280x over previous
//
#include <hip/hip_runtime.h>
#include <hip/hip_bf16.h>

typedef unsigned short u16;
typedef unsigned int u32;
typedef unsigned long long u64;
typedef short  s16x8 __attribute__((ext_vector_type(8)));
typedef float  f32x4 __attribute__((ext_vector_type(4)));
typedef u32    u32x4 __attribute__((ext_vector_type(4)));
typedef u32    u32x2 __attribute__((ext_vector_type(2)));

#define T_STEPS 512
#define BATCH   32
#define HID     512
#define EMBD    300
#define NGATE   2048

// ---- workspace layout (bytes) ----
#define XZ_OFF   0ull
#define XZ_BYTES (512ull*32*2048*4)          // 134,217,728  f32 [t][b][4H]
#define UB_OFF   (XZ_OFF + XZ_BYTES)
#define UB_BYTES (2048ull*512*2)             // per-WG U LDS images (bf16, swizzled)
#define WT_OFF   (UB_OFF + UB_BYTES)
#define WT_BYTES (2048ull*320*2)             // W^T bf16 swizzled
#define HB_OFF   (WT_OFF + WT_BYTES)
#define HB_BYTES (2ull*8192*8)               // 2 slots x 8192 tagged u64 (tag<<32 | bf16x2)

__device__ inline u16 f2b(float f) {
  u32 u = __builtin_bit_cast(u32, f);
  return (u16)((u + 0x7fffu + ((u >> 16) & 1u)) >> 16);
}

// ---------- pack W: [300][2048] f32 -> wt[n][kpad=320] bf16 swizzled ----------
__global__ __launch_bounds__(64) void pack_w(const float* __restrict__ W, u16* __restrict__ wt) {
  int n = blockIdx.x;
  for (int i = 0; i < 5; ++i) {
    int k = i * 64 + threadIdx.x;
    float v = (k < EMBD) ? W[(size_t)k * NGATE + n] : 0.f;
    u32 off = ((u32)(2 * k)) ^ (((u32)(n & 7)) << 4);
    *(u16*)((char*)wt + (size_t)n * 640 + off) = f2b(v);
  }
}

// ---------- pack U: per-worker col-major swizzled bf16 LDS image ----------
__global__ __launch_bounds__(64) void pack_u(const float* __restrict__ U, u16* __restrict__ ub) {
  int blk = blockIdx.x;             // = w*64 + nl
  int w = blk >> 6, nl = blk & 63;
  int gcol = (nl & 3) * 512 + w * 16 + (nl >> 2);
  for (int i = 0; i < 8; ++i) {
    int k = i * 64 + threadIdx.x;
    float v = U[(size_t)k * NGATE + gcol];
    u32 off = ((u32)(2 * k)) ^ (((u32)(nl & 7)) << 4);
    *(u16*)((char*)ub + (size_t)blk * 1024 + off) = f2b(v);
  }
}

// ---------- phase 1: xz[t][b][n] = emb[tok] @ W + bias ----------
__global__ __launch_bounds__(256) void xz_gemm(const int* __restrict__ tokens,
                                               const float* __restrict__ emb,
                                               const u16* __restrict__ wt,
                                               const float* __restrict__ bias,
                                               float* __restrict__ xz) {
  extern __shared__ char smem[];
  const int tid = threadIdx.x;
  const int lane = tid & 63, wv = tid >> 6;
  const int m0 = (blockIdx.x >> 5) * 64;
  const int n0 = (blockIdx.x & 31) * 64;

  { // stage A: 64 emb rows gathered, f32 -> bf16
    int row = tid >> 2, q = tid & 3;
    int tok = tokens[m0 + row];
    const float* er = emb + (size_t)tok * EMBD;
    for (int i = 0; i < 10; ++i) {
      int k = q * 80 + i * 8;
      float4 lo = {0, 0, 0, 0}, hi = {0, 0, 0, 0};
      if (k <= 296) lo = *(const float4*)(er + k);
      if (k <= 292) hi = *(const float4*)(er + k + 4);
      u16 u[8] = {f2b(lo.x), f2b(lo.y), f2b(lo.z), f2b(lo.w),
                  f2b(hi.x), f2b(hi.y), f2b(hi.z), f2b(hi.w)};
      int kc = q * 10 + i;
      *(uint4*)(smem + kc * 1040 + row * 16) = *(uint4*)u;
    }
  }
  { // stage B: linear copy of pre-swizzled wt panel
    const uint4* src = (const uint4*)((const char*)wt + (size_t)n0 * 640);
    for (int i = 0; i < 10; ++i)
      *(uint4*)(smem + 41600 + (i * 256 + tid) * 16) = src[i * 256 + tid];
  }
  __syncthreads();

  const int mq = wv >> 1, nq = wv & 1;
  const int arow = lane & 15, kq4 = lane >> 4;
  f32x4 acc[2][2] = {};
#pragma unroll
  for (int ks = 0; ks < 10; ++ks) {
    s16x8 af[2], bfr[2];
#pragma unroll
    for (int mt = 0; mt < 2; ++mt) {
      int row = mq * 32 + mt * 16 + arow;
      int kc = ks * 4 + kq4;
      af[mt] = *(const s16x8*)(smem + kc * 1040 + row * 16);
    }
#pragma unroll
    for (int nt = 0; nt < 2; ++nt) {
      int nl = nq * 32 + nt * 16 + arow;
      u32 kb = (u32)(ks * 64 + (kq4 << 4));
      bfr[nt] = *(const s16x8*)(smem + 41600 + nl * 640 + (kb ^ (((u32)(nl & 7)) << 4)));
    }
#pragma unroll
    for (int mt = 0; mt < 2; ++mt)
#pragma unroll
      for (int nt = 0; nt < 2; ++nt)
        acc[mt][nt] = __builtin_amdgcn_mfma_f32_16x16x32_bf16(af[mt], bfr[nt], acc[mt][nt], 0, 0, 0);
  }
#pragma unroll
  for (int mt = 0; mt < 2; ++mt)
#pragma unroll
    for (int nt = 0; nt < 2; ++nt) {
      int gn = n0 + nq * 32 + nt * 16 + arow;
      float bv = bias[gn];
#pragma unroll
      for (int r = 0; r < 4; ++r) {
        int gm = m0 + mq * 32 + mt * 16 + (kq4 << 2) + r;
        int tt = gm & 511, bb = gm >> 9;
        xz[((size_t)(tt * 32 + bb)) * NGATE + gn] = acc[mt][nt][r] + bv;
      }
    }
}

// ---------- phase 2: persistent 32-WG recurrent kernel, tag-in-payload data-flow sync ----
// LDS: [0,64K) U slice; [64K,96K) h tile [32][512] bf16 swizzled; [96K, +8.7K) zlds f32.
// h exchange: hbuf = 2 slots x 8192 u64; word p = b*256+j2 = (tag << 32) | bf16{2*j2, 2*j2+1}.
// No flags, no fences: readers poll tags on the data itself (one MALL crossing per step).
__global__ __launch_bounds__(256) void lstm_persist(const float* __restrict__ xz,
                                                    const u16* __restrict__ ub,
                                                    u64* __restrict__ hbuf,
                                                    float* __restrict__ out) {
  extern __shared__ char smem[];
  char*  hl   = smem + 65536;                // h tile, 32KB
  float* zlds = (float*)(smem + 98304);      // [32][68] f32
  const int tid = threadIdx.x;
  const int lane = tid & 63, wv = tid >> 6;
  const int wg = blockIdx.x;

  { // stage pre-swizzled U slice: 64KB linear copy
    const uint4* src = (const uint4*)(ub + (size_t)wg * 32768);
    uint4* dst = (uint4*)smem;
    for (int i = 0; i < 16; ++i) dst[i * 256 + tid] = src[i * 256 + tid];
  }
  __syncthreads();

  const int b_g = tid & 31;
  const int pp  = tid >> 5;                  // h-cols 2pp, 2pp+1 of this WG's 16
  const int arow = lane & 15, kq = lane >> 4;
  const int nl = wv * 16 + (lane & 15);
  const u32 bswz = ((u32)(nl & 7)) << 4;
  const int j0 = wg * 16;
  float c0 = 0.f, c1 = 0.f;

  // poll voffsets (loop-invariant): load l covers tagged words p = l*512 + 2*tid (+1)
  const u32 vo0 = (u32)(tid * 16 + 1 * 4096), vo1 = (u32)(tid * 16 + 3 * 4096);
  const u32 vo2 = (u32)(tid * 16 + 5 * 4096), vo3 = (u32)(tid * 16 + 7 * 4096);
  const u32 vo4 = (u32)(tid * 16 + 9 * 4096), vo5 = (u32)(tid * 16 + 11 * 4096);
  const u32 vo6 = (u32)(tid * 16 + 13 * 4096), vo7 = (u32)(tid * 16 + 15 * 4096);
  const u32 brow0 = (u32)(tid >> 7);
  const u32 colb  = (u32)(((2 * tid) & 255) * 4);

  float xzv[2][4];
  { // prefetch xz for t=0
    const float* p = xz + (size_t)b_g * NGATE + j0;
#pragma unroll
    for (int e = 0; e < 2; ++e) {
      int jl = 2 * pp + e;
#pragma unroll
      for (int g = 0; g < 4; ++g) xzv[e][g] = p[g * 512 + jl];
    }
  }

  for (int t = 0; t < T_STEPS; ++t) {
    if (t > 0) {
      // ---- poll-copy h_t (tag == t) from MALL into LDS ----
      const u32 tt = (u32)t;
      const u64 sb = (u64)(uintptr_t)hbuf + (u64)((t & 1) * 65536);
      u32x4 q0, q1, q2, q3, q4, q5, q6, q7, q8, q9, q10, q11, q12, q13, q14, q15;
      int tries = 0;
      for (;;) {
        asm volatile(
          "global_load_dwordx4 %0, %16, %24 offset:-4096 sc0 sc1\n\t"
          "global_load_dwordx4 %1, %16, %24 sc0 sc1\n\t"
          "global_load_dwordx4 %2, %17, %24 offset:-4096 sc0 sc1\n\t"
          "global_load_dwordx4 %3, %17, %24 sc0 sc1\n\t"
          "global_load_dwordx4 %4, %18, %24 offset:-4096 sc0 sc1\n\t"
          "global_load_dwordx4 %5, %18, %24 sc0 sc1\n\t"
          "global_load_dwordx4 %6, %19, %24 offset:-4096 sc0 sc1\n\t"
          "global_load_dwordx4 %7, %19, %24 sc0 sc1\n\t"
          "global_load_dwordx4 %8, %20, %24 offset:-4096 sc0 sc1\n\t"
          "global_load_dwordx4 %9, %20, %24 sc0 sc1\n\t"
          "global_load_dwordx4 %10, %21, %24 offset:-4096 sc0 sc1\n\t"
          "global_load_dwordx4 %11, %21, %24 sc0 sc1\n\t"
          "global_load_dwordx4 %12, %22, %24 offset:-4096 sc0 sc1\n\t"
          "global_load_dwordx4 %13, %22, %24 sc0 sc1\n\t"
          "global_load_dwordx4 %14, %23, %24 offset:-4096 sc0 sc1\n\t"
          "global_load_dwordx4 %15, %23, %24 sc0 sc1\n\t"
          "s_waitcnt vmcnt(0)"
          : "=&v"(q0), "=&v"(q1), "=&v"(q2), "=&v"(q3),
            "=&v"(q4), "=&v"(q5), "=&v"(q6), "=&v"(q7),
            "=&v"(q8), "=&v"(q9), "=&v"(q10), "=&v"(q11),
            "=&v"(q12), "=&v"(q13), "=&v"(q14), "=&v"(q15)
          : "v"(vo0), "v"(vo1), "v"(vo2), "v"(vo3),
            "v"(vo4), "v"(vo5), "v"(vo6), "v"(vo7), "s"(sb)
          : "memory");
        u32 bad = (q0.y ^ tt) | (q0.w ^ tt) | (q1.y ^ tt) | (q1.w ^ tt) |
                  (q2.y ^ tt) | (q2.w ^ tt) | (q3.y ^ tt) | (q3.w ^ tt) |
                  (q4.y ^ tt) | (q4.w ^ tt) | (q5.y ^ tt) | (q5.w ^ tt) |
                  (q6.y ^ tt) | (q6.w ^ tt) | (q7.y ^ tt) | (q7.w ^ tt) |
                  (q8.y ^ tt) | (q8.w ^ tt) | (q9.y ^ tt) | (q9.w ^ tt) |
                  (q10.y ^ tt) | (q10.w ^ tt) | (q11.y ^ tt) | (q11.w ^ tt) |
                  (q12.y ^ tt) | (q12.w ^ tt) | (q13.y ^ tt) | (q13.w ^ tt) |
                  (q14.y ^ tt) | (q14.w ^ tt) | (q15.y ^ tt) | (q15.w ^ tt);
        if (bad == 0 || ++tries > 65536) break;   // cap: fail loudly, never hang
      }
#define HWRITE(L, Q) { u32 b_ = 2u * (L) + brow0;                              \
        u32 off_ = b_ * 1024u + (colb ^ ((b_ & 7u) << 4));                     \
        u32x2 v_; v_.x = (Q).x; v_.y = (Q).z;                                  \
        *(u32x2*)(hl + off_) = v_; }
      HWRITE(0, q0)  HWRITE(1, q1)  HWRITE(2, q2)  HWRITE(3, q3)
      HWRITE(4, q4)  HWRITE(5, q5)  HWRITE(6, q6)  HWRITE(7, q7)
      HWRITE(8, q8)  HWRITE(9, q9)  HWRITE(10, q10) HWRITE(11, q11)
      HWRITE(12, q12) HWRITE(13, q13) HWRITE(14, q14) HWRITE(15, q15)
#undef HWRITE
    }
    __syncthreads();   // A: h_lds ready

    if (t > 0) {  // z = h @ U_slice, A-fragments from LDS (swizzled)
      f32x4 acc0 = {0, 0, 0, 0}, acc1 = {0, 0, 0, 0};
      const u32 aswz = ((u32)(arow & 7)) << 4;
#pragma unroll
      for (int ks = 0; ks < 16; ++ks) {
        u32 kb = (u32)(ks * 64 + (kq << 4));
        s16x8 a0 = *(const s16x8*)(hl + arow * 1024 + (kb ^ aswz));
        s16x8 a1 = *(const s16x8*)(hl + (arow + 16) * 1024 + (kb ^ aswz));
        s16x8 bb = *(const s16x8*)(smem + nl * 1024 + (kb ^ bswz));
        acc0 = __builtin_amdgcn_mfma_f32_16x16x32_bf16(a0, bb, acc0, 0, 0, 0);
        acc1 = __builtin_amdgcn_mfma_f32_16x16x32_bf16(a1, bb, acc1, 0, 0, 0);
      }
      int rb = kq * 4;
#pragma unroll
      for (int r = 0; r < 4; ++r) {
        zlds[(rb + r) * 68 + nl] = acc0[r];
        zlds[(rb + r + 16) * 68 + nl] = acc1[r];
      }
    }
    __syncthreads();   // B: zlds ready

    // gates: thread handles (b_g, 2pp) and (b_g, 2pp+1)
    float hov[2], cov[2];
    float4 z0 = {0, 0, 0, 0}, z1 = {0, 0, 0, 0};
    if (t > 0) {
      z0 = *(const float4*)&zlds[b_g * 68 + 8 * pp];
      z1 = *(const float4*)&zlds[b_g * 68 + 8 * pp + 4];
    }
#pragma unroll
    for (int e = 0; e < 2; ++e) {
      float4 zr = e ? z1 : z0;
      float zi = zr.x + xzv[e][0];
      float zf = zr.y + xzv[e][1];
      float zg = zr.z + xzv[e][2];
      float zo = zr.w + xzv[e][3];
      float ig = 1.f / (1.f + __expf(-zi));
      float fg = 1.f / (1.f + __expf(-zf));
      float gg = 1.f - 2.f / (__expf(2.f * zg) + 1.f);
      float og = 1.f / (1.f + __expf(-zo));
      float cc = e ? c1 : c0;
      cc = fg * cc + ig * gg;
      float hh = og * (1.f - 2.f / (__expf(2.f * cc) + 1.f));
      if (e) c1 = cc; else c0 = cc;
      hov[e] = hh; cov[e] = cc;
    }

    if (t < T_STEPS - 1) {
      // publish h_{t+1}: tagged u64, relaxed agent atomic (MALL write-through, no drain)
      u64 hw = ((u64)(u32)(t + 1) << 32) |
               (u64)((u32)f2b(hov[0]) | ((u32)f2b(hov[1]) << 16));
      __hip_atomic_store(&hbuf[(size_t)((t + 1) & 1) * 8192 + b_g * 256 + wg * 8 + pp],
                         hw, __ATOMIC_RELAXED, __HIP_MEMORY_SCOPE_AGENT);
      { // prefetch next xz
        const float* p = xz + ((size_t)(t + 1) * 32 + b_g) * NGATE + j0;
#pragma unroll
        for (int e = 0; e < 2; ++e) {
          int jl = 2 * pp + e;
#pragma unroll
          for (int g = 0; g < 4; ++g) xzv[e][g] = p[g * 512 + jl];
        }
      }
    } else {
#pragma unroll
      for (int e = 0; e < 2; ++e) {
        int jl = 2 * pp + e;
        out[b_g * 512 + j0 + jl] = hov[e];
        out[16384 + b_g * 512 + j0 + jl] = cov[e];
      }
    }
    __syncthreads();   // C: zlds consumed; h_lds reads done before next poll overwrites
  }
}

extern "C" void kernel_launch(void* const* d_in, const int* in_sizes, int n_in,
                              void* d_out, int out_size, void* d_ws, size_t ws_size,
                              hipStream_t stream) {
  const int*   tokens = (const int*)d_in[0];
  const float* emb    = (const float*)d_in[1];
  const float* W      = (const float*)d_in[2];
  const float* U      = (const float*)d_in[3];
  const float* bias   = (const float*)d_in[4];
  float* out = (float*)d_out;
  char*  ws  = (char*)d_ws;

  float* xz   = (float*)(ws + XZ_OFF);
  u16*   ub   = (u16*)(ws + UB_OFF);
  u16*   wt   = (u16*)(ws + WT_OFF);
  u64*   hbuf = (u64*)(ws + HB_OFF);

  pack_w<<<2048, 64, 0, stream>>>(W, wt);
  pack_u<<<2048, 64, 0, stream>>>(U, ub);
  xz_gemm<<<8192, 256, 82560, stream>>>(tokens, emb, wt, bias, xz);
  lstm_persist<<<32, 256, 107008, stream>>>(xz, ub, hbuf, out);
}

// Round 7
// 1741.686 us; speedup vs baseline: 2.7542x; 1.1831x over previous
//
#include <hip/hip_runtime.h>
#include <hip/hip_bf16.h>

typedef unsigned short u16;
typedef unsigned int u32;
typedef unsigned long long u64;
typedef short  s16x8 __attribute__((ext_vector_type(8)));
typedef float  f32x4 __attribute__((ext_vector_type(4)));
typedef u32    u32x4 __attribute__((ext_vector_type(4)));

#define T_STEPS 512
#define BATCH   32
#define HID     512
#define EMBD    300
#define NGATE   2048

// ---- workspace layout (bytes) ----
#define XZ_OFF   0ull
#define XZ_BYTES (512ull*32*2048*4)          // 134,217,728  f32 [t][b][wg][g][16]
#define UB_OFF   (XZ_OFF + XZ_BYTES)
#define UB_BYTES (2048ull*512*2)             // per-WG U LDS images (bf16, swizzled)
#define WT_OFF   (UB_OFF + UB_BYTES)
#define WT_BYTES (2048ull*320*2)             // W^T bf16 swizzled
#define HB_OFF   (WT_OFF + WT_BYTES)
#define HB_BYTES (2ull*8192*4)               // 2 slots x 8192 u32 of LSB-tagged bf16 pairs

__device__ inline u16 f2b(float f) {
  u32 u = __builtin_bit_cast(u32, f);
  return (u16)((u + 0x7fffu + ((u >> 16) & 1u)) >> 16);
}

__device__ inline void st32_agent(u32* p, u32 v) {
  __hip_atomic_store(p, v, __ATOMIC_RELAXED, __HIP_MEMORY_SCOPE_AGENT);
}

// ---------- pack W: [300][2048] f32 -> wt[n][kpad=320] bf16 swizzled ----------
__global__ __launch_bounds__(64) void pack_w(const float* __restrict__ W, u16* __restrict__ wt) {
  int n = blockIdx.x;
  for (int i = 0; i < 5; ++i) {
    int k = i * 64 + threadIdx.x;
    float v = (k < EMBD) ? W[(size_t)k * NGATE + n] : 0.f;
    u32 off = ((u32)(2 * k)) ^ (((u32)(n & 7)) << 4);
    *(u16*)((char*)wt + (size_t)n * 640 + off) = f2b(v);
  }
}

// ---------- pack U: per-worker col-major swizzled bf16 LDS image ----------
__global__ __launch_bounds__(64) void pack_u(const float* __restrict__ U, u16* __restrict__ ub) {
  int blk = blockIdx.x;             // = w*64 + nl
  int w = blk >> 6, nl = blk & 63;
  int gcol = (nl & 3) * 512 + w * 16 + (nl >> 2);
  for (int i = 0; i < 8; ++i) {
    int k = i * 64 + threadIdx.x;
    float v = U[(size_t)k * NGATE + gcol];
    u32 off = ((u32)(2 * k)) ^ (((u32)(nl & 7)) << 4);
    *(u16*)((char*)ub + (size_t)blk * 1024 + off) = f2b(v);
  }
}

// ---------- phase 1: xz = emb[tok] @ W + bias, layout [t][b][wg][g][16] ----------
__global__ __launch_bounds__(256) void xz_gemm(const int* __restrict__ tokens,
                                               const float* __restrict__ emb,
                                               const u16* __restrict__ wt,
                                               const float* __restrict__ bias,
                                               float* __restrict__ xz) {
  extern __shared__ char smem[];
  const int tid = threadIdx.x;
  const int lane = tid & 63, wv = tid >> 6;
  const int m0 = (blockIdx.x >> 5) * 64;
  const int n0 = (blockIdx.x & 31) * 64;

  { // stage A: 64 emb rows gathered, f32 -> bf16
    int row = tid >> 2, q = tid & 3;
    int tok = tokens[m0 + row];
    const float* er = emb + (size_t)tok * EMBD;
    for (int i = 0; i < 10; ++i) {
      int k = q * 80 + i * 8;
      float4 lo = {0, 0, 0, 0}, hi = {0, 0, 0, 0};
      if (k <= 296) lo = *(const float4*)(er + k);
      if (k <= 292) hi = *(const float4*)(er + k + 4);
      u16 u[8] = {f2b(lo.x), f2b(lo.y), f2b(lo.z), f2b(lo.w),
                  f2b(hi.x), f2b(hi.y), f2b(hi.z), f2b(hi.w)};
      int kc = q * 10 + i;
      *(uint4*)(smem + kc * 1040 + row * 16) = *(uint4*)u;
    }
  }
  { // stage B: linear copy of pre-swizzled wt panel
    const uint4* src = (const uint4*)((const char*)wt + (size_t)n0 * 640);
    for (int i = 0; i < 10; ++i)
      *(uint4*)(smem + 41600 + (i * 256 + tid) * 16) = src[i * 256 + tid];
  }
  __syncthreads();

  const int mq = wv >> 1, nq = wv & 1;
  const int arow = lane & 15, kq4 = lane >> 4;
  f32x4 acc[2][2] = {};
#pragma unroll
  for (int ks = 0; ks < 10; ++ks) {
    s16x8 af[2], bfr[2];
#pragma unroll
    for (int mt = 0; mt < 2; ++mt) {
      int row = mq * 32 + mt * 16 + arow;
      int kc = ks * 4 + kq4;
      af[mt] = *(const s16x8*)(smem + kc * 1040 + row * 16);
    }
#pragma unroll
    for (int nt = 0; nt < 2; ++nt) {
      int nl = nq * 32 + nt * 16 + arow;
      u32 kb = (u32)(ks * 64 + (kq4 << 4));
      bfr[nt] = *(const s16x8*)(smem + 41600 + nl * 640 + (kb ^ (((u32)(nl & 7)) << 4)));
    }
#pragma unroll
    for (int mt = 0; mt < 2; ++mt)
#pragma unroll
      for (int nt = 0; nt < 2; ++nt)
        acc[mt][nt] = __builtin_amdgcn_mfma_f32_16x16x32_bf16(af[mt], bfr[nt], acc[mt][nt], 0, 0, 0);
  }
#pragma unroll
  for (int mt = 0; mt < 2; ++mt)
#pragma unroll
    for (int nt = 0; nt < 2; ++nt) {
      int gn = n0 + nq * 32 + nt * 16 + arow;
      float bv = bias[gn];
      int g = gn >> 9, j = gn & 511;
      size_t inner = (size_t)((j >> 4) * 64 + g * 16 + (j & 15));
#pragma unroll
      for (int r = 0; r < 4; ++r) {
        int gm = m0 + mq * 32 + mt * 16 + (kq4 << 2) + r;
        int tt = gm & 511, bb = gm >> 9;       // tokens flat = b*T + t
        xz[(size_t)(tt * 32 + bb) * 2048 + inner] = acc[mt][nt][r] + bv;
      }
    }
}

// ---------- phase 2: persistent 32-WG recurrent kernel ----------
// Sync: h stored as bf16 with LSB forced to tag bits tg = ((t>>1)+1)&3 (lo bf16 LSB
// = tg&1, hi bf16 LSB = tg>>1). u32 stores are atomic -> no torn tags. Readers spin
// until every u32 in the slot carries the expected tag. 2 slots alternate; writer
// can only overwrite slot words after all WGs consumed them (progress invariant),
// and the reader's step-by-step tag walk on each address (coherence-ordered) blocks
// replay-stale/zero-init false matches. hbuf is zeroed per launch (tag 0 -> first
// matching expectation is t=6/7, by which time h_2..h_5 were observed on-chain).
__global__ __launch_bounds__(256) void lstm_persist(const float* __restrict__ xz,
                                                    const u16* __restrict__ ub,
                                                    u32* __restrict__ hbuf,
                                                    float* __restrict__ out) {
  extern __shared__ char smem[];
  char*  hl   = smem + 65536;                // h tile [32][512] bf16 swizzled, 32KB
  float* zlds = (float*)(smem + 98304);      // [32][67] f32
  const int tid = threadIdx.x;
  const int lane = tid & 63, wv = tid >> 6;
  const int wg = blockIdx.x;

  { // stage pre-swizzled U slice: 64KB linear copy
    const uint4* src = (const uint4*)(ub + (size_t)wg * 32768);
    uint4* dst = (uint4*)smem;
    for (int i = 0; i < 16; ++i) dst[i * 256 + tid] = src[i * 256 + tid];
  }
  __syncthreads();

  const int b_g = tid & 31;
  const int pp  = tid >> 5;                  // h-cols 2pp, 2pp+1 of this WG's 16
  const int arow = lane & 15, kq = lane >> 4;
  const int nl = wv * 16 + (lane & 15);
  const u32 bswz = ((u32)(nl & 7)) << 4;
  const int j0 = wg * 16;
  float c0 = 0.f, c1 = 0.f;

  // poll address bases: thread covers u32 idx = tid*4 + l*1024, l=0..7
  const u32 vo0 = (u32)(tid * 16 + 1 * 4096), vo1 = (u32)(tid * 16 + 3 * 4096);
  const u32 vo2 = (u32)(tid * 16 + 5 * 4096), vo3 = (u32)(tid * 16 + 7 * 4096);
  const u32 hrow0 = (u32)(tid >> 6);
  const u32 hcolb = (u32)((tid & 63) * 16);

  float xzv[2][4];
  { // prefetch xz for t=0: [0][b_g][wg][g][2pp..]
    const float* p = xz + (size_t)b_g * 2048 + wg * 64 + 2 * pp;
#pragma unroll
    for (int g = 0; g < 4; ++g) {
      float2 v = *(const float2*)(p + g * 16);
      xzv[0][g] = v.x; xzv[1][g] = v.y;
    }
  }

  for (int t = 0; t < T_STEPS; ++t) {
    if (t > 0) {
      // ---- poll-copy h_t from MALL into LDS (tags embedded in bf16 LSBs) ----
      u32 tg = (((u32)t >> 1) + 1u) & 3u;
      u32 pat = (tg & 1u) | ((tg >> 1) << 16);
      const u64 sb = (u64)(uintptr_t)hbuf + (u64)((t & 1) * 32768);
      u32x4 q0, q1, q2, q3, q4, q5, q6, q7;
      int tries = 0;
      for (;;) {
        asm volatile(
          "global_load_dwordx4 %0, %8, %12 offset:-4096 sc0 sc1\n\t"
          "global_load_dwordx4 %1, %8, %12 sc0 sc1\n\t"
          "global_load_dwordx4 %2, %9, %12 offset:-4096 sc0 sc1\n\t"
          "global_load_dwordx4 %3, %9, %12 sc0 sc1\n\t"
          "global_load_dwordx4 %4, %10, %12 offset:-4096 sc0 sc1\n\t"
          "global_load_dwordx4 %5, %10, %12 sc0 sc1\n\t"
          "global_load_dwordx4 %6, %11, %12 offset:-4096 sc0 sc1\n\t"
          "global_load_dwordx4 %7, %11, %12 sc0 sc1\n\t"
          "s_waitcnt vmcnt(0)"
          : "=&v"(q0), "=&v"(q1), "=&v"(q2), "=&v"(q3),
            "=&v"(q4), "=&v"(q5), "=&v"(q6), "=&v"(q7)
          : "v"(vo0), "v"(vo1), "v"(vo2), "v"(vo3), "s"(sb)
          : "memory");
        u32 x0 = (q0.x ^ pat) | (q0.y ^ pat) | (q0.z ^ pat) | (q0.w ^ pat);
        u32 x1 = (q1.x ^ pat) | (q1.y ^ pat) | (q1.z ^ pat) | (q1.w ^ pat);
        u32 x2 = (q2.x ^ pat) | (q2.y ^ pat) | (q2.z ^ pat) | (q2.w ^ pat);
        u32 x3 = (q3.x ^ pat) | (q3.y ^ pat) | (q3.z ^ pat) | (q3.w ^ pat);
        u32 x4 = (q4.x ^ pat) | (q4.y ^ pat) | (q4.z ^ pat) | (q4.w ^ pat);
        u32 x5 = (q5.x ^ pat) | (q5.y ^ pat) | (q5.z ^ pat) | (q5.w ^ pat);
        u32 x6 = (q6.x ^ pat) | (q6.y ^ pat) | (q6.z ^ pat) | (q6.w ^ pat);
        u32 x7 = (q7.x ^ pat) | (q7.y ^ pat) | (q7.z ^ pat) | (q7.w ^ pat);
        u32 bad = (x0 | x1 | x2 | x3 | x4 | x5 | x6 | x7) & 0x00010001u;
        if (bad == 0 || ++tries > 65536) break;   // cap: fail loudly, never hang
        __builtin_amdgcn_s_sleep(1);
      }
#define HW(L, Q) { u32 r_ = hrow0 + 4u * (L);                                  \
        u32 off_ = r_ * 1024u + (hcolb ^ ((r_ & 7u) << 4));                    \
        *(u32x4*)(hl + off_) = (Q); }
      HW(0, q0) HW(1, q1) HW(2, q2) HW(3, q3)
      HW(4, q4) HW(5, q5) HW(6, q6) HW(7, q7)
#undef HW
    }
    __syncthreads();   // A: h_lds ready (also orders hl overwrite after prior-step MFMA reads)

    if (t > 0) {  // z = h @ U_slice, A-fragments from LDS (swizzled)
      f32x4 acc0 = {0, 0, 0, 0}, acc1 = {0, 0, 0, 0};
      const u32 aswz = ((u32)(arow & 7)) << 4;
#pragma unroll
      for (int ks = 0; ks < 16; ++ks) {
        u32 kb = (u32)(ks * 64 + (kq << 4));
        s16x8 a0 = *(const s16x8*)(hl + arow * 1024 + (kb ^ aswz));
        s16x8 a1 = *(const s16x8*)(hl + (arow + 16) * 1024 + (kb ^ aswz));
        s16x8 bb = *(const s16x8*)(smem + nl * 1024 + (kb ^ bswz));
        acc0 = __builtin_amdgcn_mfma_f32_16x16x32_bf16(a0, bb, acc0, 0, 0, 0);
        acc1 = __builtin_amdgcn_mfma_f32_16x16x32_bf16(a1, bb, acc1, 0, 0, 0);
      }
      int rb = kq * 4;
#pragma unroll
      for (int r = 0; r < 4; ++r) {
        zlds[(rb + r) * 67 + nl] = acc0[r];
        zlds[(rb + r + 16) * 67 + nl] = acc1[r];
      }
    }
    __syncthreads();   // B: zlds ready

    // gates: thread handles (b_g, 2pp) and (b_g, 2pp+1); zlds col nl = 4j+g
    float hov[2], cov[2];
    float zv[8] = {0, 0, 0, 0, 0, 0, 0, 0};
    if (t > 0) {
      const float* zp = &zlds[b_g * 67 + 8 * pp];
#pragma unroll
      for (int m = 0; m < 8; ++m) zv[m] = zp[m];
    }
#pragma unroll
    for (int e = 0; e < 2; ++e) {
      float zi = zv[4 * e + 0] + xzv[e][0];
      float zf = zv[4 * e + 1] + xzv[e][1];
      float zg = zv[4 * e + 2] + xzv[e][2];
      float zo = zv[4 * e + 3] + xzv[e][3];
      float ig = 1.f / (1.f + __expf(-zi));
      float fg = 1.f / (1.f + __expf(-zf));
      float gg = 1.f - 2.f / (__expf(2.f * zg) + 1.f);
      float og = 1.f / (1.f + __expf(-zo));
      float cc = e ? c1 : c0;
      cc = fg * cc + ig * gg;
      float hh = og * (1.f - 2.f / (__expf(2.f * cc) + 1.f));
      if (e) c1 = cc; else c0 = cc;
      hov[e] = hh; cov[e] = cc;
    }

    if (t < T_STEPS - 1) {
      // publish h_{t+1}: LSB-tagged bf16 pair, relaxed agent u32 store (MALL-coherent)
      u32 tg2 = (((u32)(t + 1) >> 1) + 1u) & 3u;
      u32 val = ((u32)(f2b(hov[0]) & 0xFFFEu) | (tg2 & 1u)) |
                ((((u32)(f2b(hov[1]) & 0xFFFEu)) | ((tg2 >> 1) & 1u)) << 16);
      st32_agent(&hbuf[(size_t)((t + 1) & 1) * 8192 + b_g * 256 + wg * 8 + pp], val);
      { // prefetch next xz (contiguous per-WG slice)
        const float* p = xz + ((size_t)(t + 1) * 32 + b_g) * 2048 + wg * 64 + 2 * pp;
#pragma unroll
        for (int g = 0; g < 4; ++g) {
          float2 v = *(const float2*)(p + g * 16);
          xzv[0][g] = v.x; xzv[1][g] = v.y;
        }
      }
    } else {
#pragma unroll
      for (int e = 0; e < 2; ++e) {
        int jl = 2 * pp + e;
        out[b_g * 512 + j0 + jl] = hov[e];
        out[16384 + b_g * 512 + j0 + jl] = cov[e];
      }
    }
    // no barrier here: next iteration's barrier A orders hl overwrites after this
    // step's zlds reads (every thread passes A only after finishing its gates), and
    // a WG's poll can't succeed until ALL threads (incl. same-WG) have published.
  }
}

extern "C" void kernel_launch(void* const* d_in, const int* in_sizes, int n_in,
                              void* d_out, int out_size, void* d_ws, size_t ws_size,
                              hipStream_t stream) {
  const int*   tokens = (const int*)d_in[0];
  const float* emb    = (const float*)d_in[1];
  const float* W      = (const float*)d_in[2];
  const float* U      = (const float*)d_in[3];
  const float* bias   = (const float*)d_in[4];
  float* out = (float*)d_out;
  char*  ws  = (char*)d_ws;

  float* xz   = (float*)(ws + XZ_OFF);
  u16*   ub   = (u16*)(ws + UB_OFF);
  u16*   wt   = (u16*)(ws + WT_OFF);
  u32*   hbuf = (u32*)(ws + HB_OFF);

  hipMemsetAsync(hbuf, 0, HB_BYTES, stream);   // tag-0 init: see safety proof above
  pack_w<<<2048, 64, 0, stream>>>(W, wt);
  pack_u<<<2048, 64, 0, stream>>>(U, ub);
  xz_gemm<<<8192, 256, 82560, stream>>>(tokens, emb, wt, bias, xz);
  lstm_persist<<<32, 256, 106880, stream>>>(xz, ub, hbuf, out);
}